// Round 8
// baseline (820.639 us; speedup 1.0000x reference)
//
#include <hip/hip_runtime.h>
#include <math.h>

// Problem constants (fixed shapes from setup_inputs)
constexpr int B_  = 2;
constexpr int L_  = 512;    // txt tokens
constexpr int N_  = 2048;   // img tokens (H=64, W=32)
constexpr int T_  = 2560;   // L_+N_
constexpr int D_  = 512;
constexpr int NH_ = 4;
constexpr int HD_ = 128;
constexpr int FF_ = 2048;
constexpr int SIXD = 3072;
constexpr int MROWS = B_ * T_;   // 5120
#define SCALE_ 0.08838834764831843f

// Workspace layout (floats). Packed hi/lo activations reuse the same regions.
constexpr size_t QSZ    = (size_t)B_ * NH_ * T_ * HD_;      // 2,621,440 (== B*T*D)
constexpr size_t O_ETXT = 0;
constexpr size_t O_EIMG = O_ETXT + (size_t)B_ * SIXD;       // 6144
constexpr size_t O_MOD  = O_EIMG + (size_t)B_ * SIXD;       // 12288
constexpr size_t O_EFF  = O_MOD + (size_t)B_ * NH_ * N_;    // 28672
constexpr size_t O_XN   = O_EFF + 16;                        // packed u32 XN
constexpr size_t O_Q    = O_XN + QSZ;                        // f32 Q (rope+mod applied in place)
constexpr size_t O_K    = O_Q + QSZ;                         // f32 K (pre-prep)
constexpr size_t O_V    = O_K + QSZ;                         // f32 V
constexpr size_t O_ATTN = O_V + QSZ;                         // packed u32 [5120][512]
constexpr size_t O_X2   = O_ATTN + QSZ;                      // f32 X2 (after proj); Vt bf16 during attn
constexpr size_t O_XIN2 = O_X2 + QSZ;                        // packed xin2 (after rmsmod2); Kh/Kl bf16 during attn
constexpr size_t O_H    = O_Q;   // packed u32 [5120][2048] over Q..ATTN span (4*QSZ)

typedef short bf16x8 __attribute__((ext_vector_type(8)));
typedef float f32x4 __attribute__((ext_vector_type(4)));

__device__ __forceinline__ unsigned short f2bf_rne(float x) {
  unsigned u = __float_as_uint(x);
  u += 0x7fff + ((u >> 16) & 1);
  return (unsigned short)(u >> 16);
}
// pack f32 -> (hi bf16 << 16) | lo bf16
__device__ __forceinline__ unsigned packhl(float x) {
  unsigned short h = f2bf_rne(x);
  float lof = x - __uint_as_float((unsigned)h << 16);
  unsigned short l = f2bf_rne(lof);
  return ((unsigned)h << 16) | (unsigned)l;
}

// ---------------- adaLN: e = silu(vec) @ W.T + b  (both streams) ----------------
__global__ __launch_bounds__(256) void k_adaln(const float* __restrict__ vec,
                                               const float* __restrict__ wt, const float* __restrict__ bt,
                                               const float* __restrict__ wi, const float* __restrict__ bi,
                                               float* __restrict__ ws) {
  int blk = blockIdx.x;
  int s = blk / (B_ * 12);
  int rem = blk % (B_ * 12);
  int b = rem / 12;
  int o = (rem % 12) * 256 + threadIdx.x;
  __shared__ float sv[D_];
  for (int i = threadIdx.x; i < D_; i += 256) {
    float x = vec[b * D_ + i];
    sv[i] = x / (1.0f + __expf(-x));
  }
  __syncthreads();
  const float* w = (s == 0) ? wt : wi;
  const float* bb = (s == 0) ? bt : bi;
  const float4* wrow = (const float4*)(w + (size_t)o * D_);
  float acc = 0.f;
  for (int d4 = 0; d4 < D_ / 4; ++d4) {
    float4 wv = wrow[d4];
    int d = d4 * 4;
    acc += wv.x * sv[d] + wv.y * sv[d + 1] + wv.z * sv[d + 2] + wv.w * sv[d + 3];
  }
  acc += bb[o];
  float* e = ws + ((s == 0) ? O_ETXT : O_EIMG);
  e[b * SIXD + o] = acc;
}

// ---------------- mod (bilinear upsample + affine + clip + exp) and eff ----------------
__global__ __launch_bounds__(256) void k_mod(const float* __restrict__ sspat,
                                             const float* __restrict__ mw, const float* __restrict__ mb,
                                             const float* __restrict__ stemp,
                                             float* __restrict__ ws) {
  int idx = blockIdx.x * 256 + threadIdx.x;  // B*NH*N = 16384
  if (idx < B_) {
    float s = 0.f;
    for (int h = 0; h < NH_; ++h) s += stemp[idx * NH_ + h];
    float t = fmaxf(s * 0.25f, 0.1f);
    ws[O_EFF + idx] = SCALE_ / t;
  }
  int b = idx / (NH_ * N_);
  int h = (idx / N_) % NH_;
  int n = idx % N_;
  int y = n >> 5;      // W=32
  int x = n & 31;
  float fy = (y + 0.5f) * 0.125f - 0.5f;
  float fx = (x + 0.5f) * 0.25f  - 0.5f;
  float y0f = floorf(fy), x0f = floorf(fx);
  float wy = fy - y0f, wx = fx - x0f;
  int y0 = (int)y0f, x0 = (int)x0f;
  int iy0 = y0 < 0 ? 0 : y0, iy1 = (y0 + 1) > 7 ? 7 : (y0 + 1);
  int ix0 = x0 < 0 ? 0 : x0, ix1 = (x0 + 1) > 7 ? 7 : (x0 + 1);
  const float* S = sspat + b * 64;
  float v00 = S[iy0*8+ix0], v01 = S[iy0*8+ix1];
  float v10 = S[iy1*8+ix0], v11 = S[iy1*8+ix1];
  float up = (1.f-wy)*((1.f-wx)*v00 + wx*v01) + wy*((1.f-wx)*v10 + wx*v11);
  float m = up * mw[h] + mb[h];
  m = fminf(fmaxf(m, -2.f), 2.f);
  ws[O_MOD + idx] = __expf(m);
}

// ---------------- rms + adaLN modulate -> packed hi/lo u32 ----------------
template<bool FROM_INPUT>
__global__ __launch_bounds__(256) void k_rmsmod(const float* __restrict__ txt, const float* __restrict__ img,
                                                const float* __restrict__ src_ws,
                                                const float* __restrict__ nw_txt, const float* __restrict__ nw_img,
                                                int sh_off, int sc_off,
                                                const float* __restrict__ e_ws,
                                                unsigned* __restrict__ outp) {
  int row = blockIdx.x;         // B*T rows
  int b = row / T_;
  int t = row % T_;
  bool is_txt = t < L_;
  int i0 = threadIdx.x * 2;
  float x0, x1;
  if (FROM_INPUT) {
    const float* src = is_txt ? (txt + ((size_t)b * L_ + t) * D_)
                              : (img + ((size_t)b * N_ + (t - L_)) * D_);
    x0 = src[i0]; x1 = src[i0 + 1];
  } else {
    const float* src = src_ws + (size_t)row * D_;
    x0 = src[i0]; x1 = src[i0 + 1];
  }
  float ss = x0 * x0 + x1 * x1;
  for (int off = 32; off; off >>= 1) ss += __shfl_down(ss, off, 64);
  __shared__ float red[4];
  if ((threadIdx.x & 63) == 0) red[threadIdx.x >> 6] = ss;
  __syncthreads();
  float tot = red[0] + red[1] + red[2] + red[3];
  float r = rsqrtf(tot * (1.0f / D_) + 1e-6f);
  const float* e = e_ws + (is_txt ? O_ETXT : O_EIMG) + (size_t)b * SIXD;
  const float* nw = is_txt ? nw_txt : nw_img;
  float y0 = x0 * r * nw[i0]     * (1.f + e[sc_off + i0])     + e[sh_off + i0];
  float y1 = x1 * r * nw[i0 + 1] * (1.f + e[sc_off + i0 + 1]) + e[sh_off + i0 + 1];
  uint2 pk; pk.x = packhl(y0); pk.y = packhl(y1);
  *(uint2*)&outp[(size_t)row * D_ + i0] = pk;
}

// ---------------- templated MFMA GEMM (unchanged) ----------------
template<int NTILE, int NTERMS, int KDIM, int NPR, int EPI>
__global__ __launch_bounds__(256) void k_gemm(
    const unsigned* __restrict__ Ap,
    const float* __restrict__ Wt, const float* __restrict__ Wi,
    const float* __restrict__ biast, const float* __restrict__ biasi,
    const float* __restrict__ ws_ro, float* __restrict__ wsw,
    const float* __restrict__ txt, const float* __restrict__ img,
    unsigned* __restrict__ Hp, float* __restrict__ outf) {
  int mt = blockIdx.x / NPR, nt = blockIdx.x % NPR;
  int row0 = mt * 128;
  int col0 = nt * NTILE;
  int b = row0 / T_;
  int t0 = row0 % T_;
  bool is_txt = t0 < L_;
  const float* W = is_txt ? Wt : Wi;

  __shared__ __align__(16) unsigned short ash[128 * 40];
  __shared__ __align__(16) unsigned short asl[128 * 40];
  __shared__ __align__(16) unsigned short bsh[NTILE * 40];
  __shared__ __align__(16) unsigned short bsl[(NTERMS == 3) ? NTILE * 40 : 8];

  int tid = threadIdx.x;
  int w = tid >> 6, lane = tid & 63, quad = lane >> 4, lc = lane & 15;
  int rh = w >> 1, ch = w & 1;
  constexpr int NFR = NTILE / 32;

  f32x4 acc[4][NFR];
  #pragma unroll
  for (int m = 0; m < 4; ++m)
    #pragma unroll
    for (int n = 0; n < NFR; ++n) acc[m][n] = f32x4{0.f, 0.f, 0.f, 0.f};

  for (int kt = 0; kt < KDIM / 32; ++kt) {
    {
      int r = tid >> 1, koff = (tid & 1) * 16;
      const unsigned* src = Ap + (size_t)(row0 + r) * KDIM + kt * 32 + koff;
      unsigned pw[16];
      *(uint4*)&pw[0]  = ((const uint4*)src)[0];
      *(uint4*)&pw[4]  = ((const uint4*)src)[1];
      *(uint4*)&pw[8]  = ((const uint4*)src)[2];
      *(uint4*)&pw[12] = ((const uint4*)src)[3];
      unsigned hw[8], lw[8];
      #pragma unroll
      for (int e2 = 0; e2 < 8; ++e2) {
        unsigned x = pw[2 * e2], y = pw[2 * e2 + 1];
        hw[e2] = (x >> 16) | (y & 0xffff0000u);
        lw[e2] = (x & 0xffffu) | (y << 16);
      }
      *(uint4*)&ash[r * 40 + koff]     = *(uint4*)&hw[0];
      *(uint4*)&ash[r * 40 + koff + 8] = *(uint4*)&hw[4];
      *(uint4*)&asl[r * 40 + koff]     = *(uint4*)&lw[0];
      *(uint4*)&asl[r * 40 + koff + 8] = *(uint4*)&lw[4];
    }
    {
      constexpr int NW = NTILE * 8 / 256;
      #pragma unroll
      for (int wc = 0; wc < NW; ++wc) {
        int idx = wc * 256 + tid;
        int rw = idx >> 3, c4 = idx & 7;
        float4 v = *(const float4*)(W + (size_t)(col0 + rw) * KDIM + kt * 32 + c4 * 4);
        ushort4 hh;
        hh.x = f2bf_rne(v.x); hh.y = f2bf_rne(v.y); hh.z = f2bf_rne(v.z); hh.w = f2bf_rne(v.w);
        *(ushort4*)&bsh[rw * 40 + c4 * 4] = hh;
        if (NTERMS == 3) {
          ushort4 ll;
          ll.x = f2bf_rne(v.x - __uint_as_float((unsigned)hh.x << 16));
          ll.y = f2bf_rne(v.y - __uint_as_float((unsigned)hh.y << 16));
          ll.z = f2bf_rne(v.z - __uint_as_float((unsigned)hh.z << 16));
          ll.w = f2bf_rne(v.w - __uint_as_float((unsigned)hh.w << 16));
          *(ushort4*)&bsl[rw * 40 + c4 * 4] = ll;
        }
      }
    }
    __syncthreads();

    bf16x8 afh[4], afl[4];
    #pragma unroll
    for (int m = 0; m < 4; ++m) {
      int ar = rh * 64 + m * 16 + lc;
      afh[m] = *(const bf16x8*)&ash[ar * 40 + quad * 8];
      afl[m] = *(const bf16x8*)&asl[ar * 40 + quad * 8];
    }
    #pragma unroll
    for (int n = 0; n < NFR; ++n) {
      int br = ch * (NTILE / 2) + n * 16 + lc;
      bf16x8 bh = *(const bf16x8*)&bsh[br * 40 + quad * 8];
      if (NTERMS == 3) {
        bf16x8 bl = *(const bf16x8*)&bsl[br * 40 + quad * 8];
        #pragma unroll
        for (int m = 0; m < 4; ++m) {
          acc[m][n] = __builtin_amdgcn_mfma_f32_16x16x32_bf16(afl[m], bh, acc[m][n], 0, 0, 0);
          acc[m][n] = __builtin_amdgcn_mfma_f32_16x16x32_bf16(afh[m], bl, acc[m][n], 0, 0, 0);
          acc[m][n] = __builtin_amdgcn_mfma_f32_16x16x32_bf16(afh[m], bh, acc[m][n], 0, 0, 0);
        }
      } else {
        #pragma unroll
        for (int m = 0; m < 4; ++m) {
          acc[m][n] = __builtin_amdgcn_mfma_f32_16x16x32_bf16(afl[m], bh, acc[m][n], 0, 0, 0);
          acc[m][n] = __builtin_amdgcn_mfma_f32_16x16x32_bf16(afh[m], bh, acc[m][n], 0, 0, 0);
        }
      }
    }
    __syncthreads();
  }

  const float* e = ws_ro + (is_txt ? O_ETXT : O_EIMG) + (size_t)b * SIXD;
  const float* bias = is_txt ? biast : biasi;
  #pragma unroll
  for (int m = 0; m < 4; ++m) {
    #pragma unroll
    for (int n = 0; n < NFR; ++n) {
      #pragma unroll
      for (int r = 0; r < 4; ++r) {
        int rg = row0 + rh * 64 + m * 16 + quad * 4 + r;
        int cg = col0 + ch * (NTILE / 2) + n * 16 + lc;
        float val = acc[m][n][r];
        int tt = rg % T_;
        if (EPI == 0) {
          int which = cg >> 9, h = (cg >> 7) & 3, dd = cg & 127;
          float* dst = wsw + (which == 0 ? O_Q : which == 1 ? O_K : O_V)
                     + (((size_t)b * NH_ + h) * T_ + tt) * HD_ + dd;
          *dst = val;
        } else if (EPI == 1) {
          float g = e[1024 + cg];
          float res = is_txt ? txt[((size_t)b * L_ + tt) * D_ + cg]
                             : img[((size_t)b * N_ + (tt - L_)) * D_ + cg];
          wsw[O_X2 + (size_t)rg * D_ + cg] = res + g * val;
        } else if (EPI == 2) {
          float x = val + bias[cg];
          float z = 0.7978845608028654f * (x + 0.044715f * x * x * x);
          z = fminf(fmaxf(z, -40.f), 40.f);
          float u = __expf(-2.f * z);
          float th = (1.f - u) / (1.f + u);
          Hp[(size_t)rg * FF_ + cg] = packhl(0.5f * x * (1.f + th));
        } else {
          float g = e[2560 + cg];
          float v2 = ws_ro[O_X2 + (size_t)rg * D_ + cg] + g * (val + bias[cg]);
          size_t oi = is_txt ? ((size_t)b * L_ + tt) * D_ + cg
                             : (size_t)B_ * L_ * D_ + ((size_t)b * N_ + (tt - L_)) * D_ + cg;
          outf[oi] = v2;
        }
      }
    }
  }
}

// ---------------- prep: rope+mod on Q (in place f32), K -> pre-split bf16 hi/lo ----------------
__global__ __launch_bounds__(256) void k_prep(float* __restrict__ wsw, const float* __restrict__ rope) {
  int idx = blockIdx.x * 256 + threadIdx.x;  // B*NH*T*64 = 1,310,720
  int i = idx & 63;
  int p = idx >> 6;                 // bh*T + t
  int t = p % T_;
  int bh = p / T_;
  size_t base = (size_t)p * HD_ + 2 * i;
  float* Q = wsw + O_Q;
  float* K = wsw + O_K;
  float k0 = K[base], k1 = K[base + 1];
  if (t >= L_) {
    int n = t - L_;
    float c = rope[(size_t)n * HD_ + 2 * i];
    float s = rope[(size_t)n * HD_ + 2 * i + 1];
    float m = wsw[O_MOD + (size_t)bh * N_ + n];
    float q0 = Q[base], q1 = Q[base + 1];
    Q[base]     = (q0 * c - q1 * s) * m;
    Q[base + 1] = (q1 * c + q0 * s) * m;
    float nk0 = (k0 * c - k1 * s) * m;
    float nk1 = (k1 * c + k0 * s) * m;
    k0 = nk0; k1 = nk1;
  }
  unsigned short h0 = f2bf_rne(k0), h1 = f2bf_rne(k1);
  unsigned short l0 = f2bf_rne(k0 - __uint_as_float((unsigned)h0 << 16));
  unsigned short l1 = f2bf_rne(k1 - __uint_as_float((unsigned)h1 << 16));
  unsigned* KH32 = (unsigned*)(wsw + O_XIN2);
  unsigned* KL32 = KH32 + QSZ / 2;
  KH32[(size_t)p * 64 + i] = (unsigned)h0 | ((unsigned)h1 << 16);
  KL32[(size_t)p * 64 + i] = (unsigned)l0 | ((unsigned)l1 << 16);
}

// ---------------- V f32 [bh][t][128] -> Vt bf16 [bh][d][T] (tiled transpose) ----------------
__global__ __launch_bounds__(256) void k_vt(const float* __restrict__ ws_ro, float* __restrict__ wsw) {
  int bh = blockIdx.x & 7;
  int tt = blockIdx.x >> 3;      // 0..39
  int t0 = tt * 64;
  __shared__ unsigned short vls[128 * 72];
  int tid = threadIdx.x;
  {
    int tr = tid & 63, dc = tid >> 6;  // dc: 0..3 (32-d chunk)
    const float4* src = (const float4*)(ws_ro + O_V + ((size_t)bh * T_ + t0 + tr) * HD_ + dc * 32);
    #pragma unroll
    for (int f = 0; f < 8; ++f) {
      float4 v = src[f];
      int d = dc * 32 + f * 4;
      vls[(d + 0) * 72 + tr] = f2bf_rne(v.x);
      vls[(d + 1) * 72 + tr] = f2bf_rne(v.y);
      vls[(d + 2) * 72 + tr] = f2bf_rne(v.z);
      vls[(d + 3) * 72 + tr] = f2bf_rne(v.w);
    }
  }
  __syncthreads();
  {
    int d = tid >> 1, th = (tid & 1) * 32;
    unsigned* Vt32 = (unsigned*)(wsw + O_X2);
    size_t obase = (((size_t)bh * HD_ + d) * T_ + t0 + th) >> 1;
    #pragma unroll
    for (int k = 0; k < 16; ++k) {
      unsigned lo = vls[d * 72 + th + 2 * k];
      unsigned hi = vls[d * 72 + th + 2 * k + 1];
      Vt32[obase + k] = lo | (hi << 16);
    }
  }
}

// ---------------- MFMA flash attention v5: barrier-free, KV frags direct from L2 ----------------
// grid = 8 bh x 40 qg = 320 blocks, 256 thr = 4 fully independent waves (16 q-rows each).
// B-fragments are contiguous 16B spans in pre-split Kh/Kl and pre-transposed Vt.
// Only LDS: wave-private P relayout buffer (no __syncthreads anywhere).
__global__ __launch_bounds__(256) void k_attn5(const float* __restrict__ ws_ro, float* __restrict__ wsw) {
  int bh = blockIdx.x & 7;            // bh-per-XCD swizzle: each head's ~2MB KV pinned to one L2
  int qg = blockIdx.x >> 3;           // 0..39
  int b = bh >> 2, h = bh & 3;
  int tid = threadIdx.x;
  int w = tid >> 6, lane = tid & 63, quad = lane >> 4, lc = lane & 15;
  int q0 = (qg * 4 + w) * 16;
  float scale = (q0 < L_) ? SCALE_ : ws_ro[O_EFF + b];

  const unsigned short* Khs = (const unsigned short*)(ws_ro + O_XIN2) + (size_t)bh * T_ * HD_;
  const unsigned short* Kls = (const unsigned short*)(ws_ro + O_XIN2) + QSZ + (size_t)bh * T_ * HD_;
  const unsigned short* Vts = (const unsigned short*)(ws_ro + O_X2) + (size_t)bh * HD_ * T_;

  __shared__ __align__(16) unsigned short ps[4 * 16 * 72];
  unsigned short* pw = &ps[w * 1152];

  // ---- Q frags direct from global f32 (scaled + hi/lo split, once) ----
  bf16x8 qh[4], ql[4];
  {
    const float* qrowp = ws_ro + O_Q + ((size_t)bh * T_ + q0 + lc) * HD_ + quad * 8;
    #pragma unroll
    for (int k2 = 0; k2 < 4; ++k2) {
      float4 a = *(const float4*)(qrowp + k2 * 32);
      float4 c = *(const float4*)(qrowp + k2 * 32 + 4);
      float v[8] = {a.x, a.y, a.z, a.w, c.x, c.y, c.z, c.w};
      #pragma unroll
      for (int e = 0; e < 8; ++e) {
        float x = v[e] * scale;
        unsigned short hh = f2bf_rne(x);
        float hf = __uint_as_float((unsigned)hh << 16);
        qh[k2][e] = (short)hh;
        ql[k2][e] = (short)f2bf_rne(x - hf);
      }
    }
  }

  f32x4 o[8];
  #pragma unroll
  for (int i = 0; i < 8; ++i) o[i] = f32x4{0.f, 0.f, 0.f, 0.f};
  float m_r[4] = {-1e30f, -1e30f, -1e30f, -1e30f};
  float l_r[4] = {0.f, 0.f, 0.f, 0.f};

  for (int kt = 0; kt < T_ / 64; ++kt) {
    const unsigned short* Kb = Khs + (size_t)kt * 64 * HD_;
    const unsigned short* Lb = Kls + (size_t)kt * 64 * HD_;
    const unsigned short* Vb = Vts + kt * 64;

    // ---- S = Q K^T, B-frags direct from global (16B contiguous per lane) ----
    f32x4 s[4];
    #pragma unroll
    for (int nt = 0; nt < 4; ++nt) s[nt] = f32x4{0.f, 0.f, 0.f, 0.f};
    #pragma unroll
    for (int k2 = 0; k2 < 4; ++k2) {
      int ko = k2 * 32 + quad * 8;
      #pragma unroll
      for (int nt = 0; nt < 4; ++nt) {
        bf16x8 kh = *(const bf16x8*)&Kb[(size_t)(nt * 16 + lc) * HD_ + ko];
        bf16x8 kl = *(const bf16x8*)&Lb[(size_t)(nt * 16 + lc) * HD_ + ko];
        s[nt] = __builtin_amdgcn_mfma_f32_16x16x32_bf16(ql[k2], kh, s[nt], 0, 0, 0);
        s[nt] = __builtin_amdgcn_mfma_f32_16x16x32_bf16(qh[k2], kl, s[nt], 0, 0, 0);
        s[nt] = __builtin_amdgcn_mfma_f32_16x16x32_bf16(qh[k2], kh, s[nt], 0, 0, 0);
      }
    }

    // ---- V frags (independent of softmax — issued early, latency overlapped) ----
    bf16x8 vb0[8], vb1[8];
    #pragma unroll
    for (int dt = 0; dt < 8; ++dt) {
      const unsigned short* vr = Vb + (size_t)(dt * 16 + lc) * T_;
      vb0[dt] = *(const bf16x8*)&vr[quad * 8];
      vb1[dt] = *(const bf16x8*)&vr[32 + quad * 8];
    }

    // ---- online softmax over 64 keys ----
    float alpha[4];
    #pragma unroll
    for (int r = 0; r < 4; ++r) {
      float rm = fmaxf(fmaxf(s[0][r], s[1][r]), fmaxf(s[2][r], s[3][r]));
      rm = fmaxf(rm, __shfl_xor(rm, 1, 64));
      rm = fmaxf(rm, __shfl_xor(rm, 2, 64));
      rm = fmaxf(rm, __shfl_xor(rm, 4, 64));
      rm = fmaxf(rm, __shfl_xor(rm, 8, 64));
      float mn = fmaxf(m_r[r], rm);
      alpha[r] = __expf(m_r[r] - mn);
      m_r[r] = mn;
      float p0 = __expf(s[0][r] - mn);
      float p1 = __expf(s[1][r] - mn);
      float p2 = __expf(s[2][r] - mn);
      float p3 = __expf(s[3][r] - mn);
      float rs = (p0 + p1) + (p2 + p3);
      rs += __shfl_xor(rs, 1, 64);
      rs += __shfl_xor(rs, 2, 64);
      rs += __shfl_xor(rs, 4, 64);
      rs += __shfl_xor(rs, 8, 64);
      l_r[r] = l_r[r] * alpha[r] + rs;
      int prow = quad * 4 + r;
      pw[prow * 72 + lc]      = f2bf_rne(p0);
      pw[prow * 72 + lc + 16] = f2bf_rne(p1);
      pw[prow * 72 + lc + 32] = f2bf_rne(p2);
      pw[prow * 72 + lc + 48] = f2bf_rne(p3);
    }
    #pragma unroll
    for (int dt = 0; dt < 8; ++dt) {
      #pragma unroll
      for (int r = 0; r < 4; ++r) o[dt][r] *= alpha[r];
    }

    // ---- P relayout (wave-private LDS: ds ordering within the wave, no barrier) ----
    bf16x8 pa0 = *(const bf16x8*)&pw[lc * 72 + quad * 8];
    bf16x8 pa1 = *(const bf16x8*)&pw[lc * 72 + 32 + quad * 8];

    // ---- O += P V ----
    #pragma unroll
    for (int dt = 0; dt < 8; ++dt) {
      o[dt] = __builtin_amdgcn_mfma_f32_16x16x32_bf16(pa0, vb0[dt], o[dt], 0, 0, 0);
      o[dt] = __builtin_amdgcn_mfma_f32_16x16x32_bf16(pa1, vb1[dt], o[dt], 0, 0, 0);
    }
  }

  // ---- normalize + pack hi/lo into ATTN [b][t][h*128+d] ----
  unsigned* ATp = (unsigned*)(wsw + O_ATTN);
  int trow0 = q0 + quad * 4;
  #pragma unroll
  for (int r = 0; r < 4; ++r) {
    float inv = 1.0f / l_r[r];
    size_t base = ((size_t)b * T_ + (trow0 + r)) * D_ + h * HD_ + lc;
    #pragma unroll
    for (int dt = 0; dt < 8; ++dt)
      ATp[base + dt * 16] = packhl(o[dt][r] * inv);
  }
}

extern "C" void kernel_launch(void* const* d_in, const int* in_sizes, int n_in,
                              void* d_out, int out_size, void* d_ws, size_t ws_size,
                              hipStream_t stream) {
  (void)in_sizes; (void)n_in; (void)out_size; (void)ws_size;
  const float* txt    = (const float*)d_in[0];
  const float* img    = (const float*)d_in[1];
  const float* vec    = (const float*)d_in[2];
  const float* rope   = (const float*)d_in[3];
  const float* stemp  = (const float*)d_in[4];
  const float* sspat  = (const float*)d_in[5];
  const float* i_aw   = (const float*)d_in[6];
  const float* i_ab   = (const float*)d_in[7];
  const float* i_anw  = (const float*)d_in[8];
  const float* t_aw   = (const float*)d_in[9];
  const float* t_ab   = (const float*)d_in[10];
  const float* t_anw  = (const float*)d_in[11];
  const float* t_qkvw = (const float*)d_in[12];
  const float* i_qkvw = (const float*)d_in[13];
  const float* t_outw = (const float*)d_in[14];
  const float* i_outw = (const float*)d_in[15];
  const float* modw   = (const float*)d_in[16];
  const float* modb   = (const float*)d_in[17];
  const float* i_n2w  = (const float*)d_in[18];
  const float* t_n2w  = (const float*)d_in[19];
  const float* i_f1w  = (const float*)d_in[20];
  const float* i_f1b  = (const float*)d_in[21];
  const float* i_f2w  = (const float*)d_in[22];
  const float* i_f2b  = (const float*)d_in[23];
  const float* t_f1w  = (const float*)d_in[24];
  const float* t_f1b  = (const float*)d_in[25];
  const float* t_f2w  = (const float*)d_in[26];
  const float* t_f2b  = (const float*)d_in[27];
  float* ws = (float*)d_ws;
  float* out = (float*)d_out;
  unsigned* XNp   = (unsigned*)(ws + O_XN);
  unsigned* ATTNp = (unsigned*)(ws + O_ATTN);
  unsigned* XIN2p = (unsigned*)(ws + O_XIN2);
  unsigned* Hpp   = (unsigned*)(ws + O_H);

  hipLaunchKernelGGL(k_adaln, dim3(48), dim3(256), 0, stream, vec, t_aw, t_ab, i_aw, i_ab, ws);
  hipLaunchKernelGGL(k_mod, dim3(64), dim3(256), 0, stream, sspat, modw, modb, stemp, ws);
  hipLaunchKernelGGL((k_rmsmod<true>), dim3(MROWS), dim3(256), 0, stream,
                     txt, img, (const float*)nullptr, t_anw, i_anw, 0, 512, ws, XNp);
  // QKV: N=1536, 3-term, K=512
  hipLaunchKernelGGL((k_gemm<128, 3, 512, 12, 0>), dim3(40 * 12), dim3(256), 0, stream,
                     XNp, t_qkvw, i_qkvw, nullptr, nullptr, ws, ws, txt, img, nullptr, nullptr);
  hipLaunchKernelGGL(k_prep, dim3(5120), dim3(256), 0, stream, ws, rope);
  hipLaunchKernelGGL(k_vt, dim3(320), dim3(256), 0, stream, ws, ws);
  hipLaunchKernelGGL(k_attn5, dim3(320), dim3(256), 0, stream, ws, ws);
  // proj: N=512, 2-term, K=512
  hipLaunchKernelGGL((k_gemm<64, 2, 512, 8, 1>), dim3(40 * 8), dim3(256), 0, stream,
                     ATTNp, t_outw, i_outw, nullptr, nullptr, ws, ws, txt, img, nullptr, nullptr);
  hipLaunchKernelGGL((k_rmsmod<false>), dim3(MROWS), dim3(256), 0, stream,
                     (const float*)nullptr, (const float*)nullptr, ws + O_X2, t_n2w, i_n2w,
                     1536, 2048, ws, XIN2p);
  // fc1: N=2048, 2-term, K=512
  hipLaunchKernelGGL((k_gemm<128, 2, 512, 16, 2>), dim3(40 * 16), dim3(256), 0, stream,
                     XIN2p, t_f1w, i_f1w, t_f1b, i_f1b, ws, ws, txt, img, Hpp, nullptr);
  // fc2: N=512, 2-term, K=2048
  hipLaunchKernelGGL((k_gemm<64, 2, 2048, 8, 3>), dim3(40 * 8), dim3(256), 0, stream,
                     Hpp, t_f2w, i_f2w, t_f2b, i_f2b, ws, ws, txt, img, nullptr, out);
}

// Round 9
// 587.590 us; speedup vs baseline: 1.3966x; 1.3966x over previous
//
#include <hip/hip_runtime.h>
#include <math.h>

typedef unsigned short ushort_t;

// Problem constants (fixed shapes from setup_inputs)
constexpr int B_  = 2;
constexpr int L_  = 512;    // txt tokens
constexpr int N_  = 2048;   // img tokens (H=64, W=32)
constexpr int T_  = 2560;   // L_+N_
constexpr int D_  = 512;
constexpr int NH_ = 4;
constexpr int HD_ = 128;
constexpr int FF_ = 2048;
constexpr int SIXD = 3072;
constexpr int MROWS = B_ * T_;   // 5120
#define SCALE_ 0.08838834764831843f

// Workspace layout (floats). Activations stored as separate bf16 hi/lo planes
// (2 ushort planes per region = same size as the old f32/u32 regions).
constexpr size_t QSZ    = (size_t)B_ * NH_ * T_ * HD_;      // 2,621,440 (== B*T*D)
constexpr size_t O_ETXT = 0;
constexpr size_t O_EIMG = O_ETXT + (size_t)B_ * SIXD;       // 6144
constexpr size_t O_MOD  = O_EIMG + (size_t)B_ * SIXD;       // 12288
constexpr size_t O_EFF  = O_MOD + (size_t)B_ * NH_ * N_;    // 28672
constexpr size_t O_XN   = O_EFF + 16;                        // xn planes (hi|lo), QSZ ushorts each
constexpr size_t O_Q    = O_XN + QSZ;                        // f32 Q (rope+mod applied in place)
constexpr size_t O_K    = O_Q + QSZ;                         // f32 K (pre-prep)
constexpr size_t O_V    = O_K + QSZ;                         // f32 V
constexpr size_t O_ATTN = O_V + QSZ;                         // attn planes (hi|lo)
constexpr size_t O_X2   = O_ATTN + QSZ;                      // f32 X2 (after proj); Vt bf16 during attn
constexpr size_t O_XIN2 = O_X2 + QSZ;                        // xin2 planes; Kh/Kl planes during attn
constexpr size_t O_H    = O_Q;   // H planes (hi|lo, 4*QSZ each) over Q..ATTN span

typedef short bf16x8 __attribute__((ext_vector_type(8)));
typedef float f32x4 __attribute__((ext_vector_type(4)));

__device__ __forceinline__ ushort_t f2bf_rne(float x) {
  unsigned u = __float_as_uint(x);
  u += 0x7fff + ((u >> 16) & 1);
  return (ushort_t)(u >> 16);
}

// ---------------- adaLN: e = silu(vec) @ W.T + b  (both streams) ----------------
__global__ __launch_bounds__(256) void k_adaln(const float* __restrict__ vec,
                                               const float* __restrict__ wt, const float* __restrict__ bt,
                                               const float* __restrict__ wi, const float* __restrict__ bi,
                                               float* __restrict__ ws) {
  int blk = blockIdx.x;
  int s = blk / (B_ * 12);
  int rem = blk % (B_ * 12);
  int b = rem / 12;
  int o = (rem % 12) * 256 + threadIdx.x;
  __shared__ float sv[D_];
  for (int i = threadIdx.x; i < D_; i += 256) {
    float x = vec[b * D_ + i];
    sv[i] = x / (1.0f + __expf(-x));
  }
  __syncthreads();
  const float* w = (s == 0) ? wt : wi;
  const float* bb = (s == 0) ? bt : bi;
  const float4* wrow = (const float4*)(w + (size_t)o * D_);
  float acc = 0.f;
  for (int d4 = 0; d4 < D_ / 4; ++d4) {
    float4 wv = wrow[d4];
    int d = d4 * 4;
    acc += wv.x * sv[d] + wv.y * sv[d + 1] + wv.z * sv[d + 2] + wv.w * sv[d + 3];
  }
  acc += bb[o];
  float* e = ws + ((s == 0) ? O_ETXT : O_EIMG);
  e[b * SIXD + o] = acc;
}

// ---------------- mod (bilinear upsample + affine + clip + exp) and eff ----------------
__global__ __launch_bounds__(256) void k_mod(const float* __restrict__ sspat,
                                             const float* __restrict__ mw, const float* __restrict__ mb,
                                             const float* __restrict__ stemp,
                                             float* __restrict__ ws) {
  int idx = blockIdx.x * 256 + threadIdx.x;  // B*NH*N = 16384
  if (idx < B_) {
    float s = 0.f;
    for (int h = 0; h < NH_; ++h) s += stemp[idx * NH_ + h];
    float t = fmaxf(s * 0.25f, 0.1f);
    ws[O_EFF + idx] = SCALE_ / t;
  }
  int b = idx / (NH_ * N_);
  int h = (idx / N_) % NH_;
  int n = idx % N_;
  int y = n >> 5;      // W=32
  int x = n & 31;
  float fy = (y + 0.5f) * 0.125f - 0.5f;
  float fx = (x + 0.5f) * 0.25f  - 0.5f;
  float y0f = floorf(fy), x0f = floorf(fx);
  float wy = fy - y0f, wx = fx - x0f;
  int y0 = (int)y0f, x0 = (int)x0f;
  int iy0 = y0 < 0 ? 0 : y0, iy1 = (y0 + 1) > 7 ? 7 : (y0 + 1);
  int ix0 = x0 < 0 ? 0 : x0, ix1 = (x0 + 1) > 7 ? 7 : (x0 + 1);
  const float* S = sspat + b * 64;
  float v00 = S[iy0*8+ix0], v01 = S[iy0*8+ix1];
  float v10 = S[iy1*8+ix0], v11 = S[iy1*8+ix1];
  float up = (1.f-wy)*((1.f-wx)*v00 + wx*v01) + wy*((1.f-wx)*v10 + wx*v11);
  float m = up * mw[h] + mb[h];
  m = fminf(fmaxf(m, -2.f), 2.f);
  ws[O_MOD + idx] = __expf(m);
}

// ---------------- rms + adaLN modulate -> bf16 hi/lo planes ----------------
template<bool FROM_INPUT>
__global__ __launch_bounds__(256) void k_rmsmod(const float* __restrict__ txt, const float* __restrict__ img,
                                                const float* __restrict__ src_ws,
                                                const float* __restrict__ nw_txt, const float* __restrict__ nw_img,
                                                int sh_off, int sc_off,
                                                const float* __restrict__ e_ws,
                                                ushort_t* __restrict__ oh, ushort_t* __restrict__ ol) {
  int row = blockIdx.x;         // B*T rows
  int b = row / T_;
  int t = row % T_;
  bool is_txt = t < L_;
  int i0 = threadIdx.x * 2;
  float x0, x1;
  if (FROM_INPUT) {
    const float* src = is_txt ? (txt + ((size_t)b * L_ + t) * D_)
                              : (img + ((size_t)b * N_ + (t - L_)) * D_);
    x0 = src[i0]; x1 = src[i0 + 1];
  } else {
    const float* src = src_ws + (size_t)row * D_;
    x0 = src[i0]; x1 = src[i0 + 1];
  }
  float ss = x0 * x0 + x1 * x1;
  for (int off = 32; off; off >>= 1) ss += __shfl_down(ss, off, 64);
  __shared__ float red[4];
  if ((threadIdx.x & 63) == 0) red[threadIdx.x >> 6] = ss;
  __syncthreads();
  float tot = red[0] + red[1] + red[2] + red[3];
  float r = rsqrtf(tot * (1.0f / D_) + 1e-6f);
  const float* e = e_ws + (is_txt ? O_ETXT : O_EIMG) + (size_t)b * SIXD;
  const float* nw = is_txt ? nw_txt : nw_img;
  float y0 = x0 * r * nw[i0]     * (1.f + e[sc_off + i0])     + e[sh_off + i0];
  float y1 = x1 * r * nw[i0 + 1] * (1.f + e[sc_off + i0 + 1]) + e[sh_off + i0 + 1];
  ushort_t h0 = f2bf_rne(y0), h1 = f2bf_rne(y1);
  ushort_t l0 = f2bf_rne(y0 - __uint_as_float((unsigned)h0 << 16));
  ushort_t l1 = f2bf_rne(y1 - __uint_as_float((unsigned)h1 << 16));
  *(unsigned*)&oh[(size_t)row * D_ + i0] = (unsigned)h0 | ((unsigned)h1 << 16);
  *(unsigned*)&ol[(size_t)row * D_ + i0] = (unsigned)l0 | ((unsigned)l1 << 16);
}

// ---------------- templated MFMA GEMM: A from pre-split bf16 hi/lo planes ----------------
// NTERMS=2: (Ah+Al).Wh ; NTERMS=3: + Ah.Wl (for QKV accuracy).
// EPI: 0=QKV scatter, 1=proj gate+residual->X2, 2=fc1 bias+gelu->H planes, 3=fc2 bias+gate+residual->out
template<int NTILE, int NTERMS, int KDIM, int NPR, int EPI>
__global__ __launch_bounds__(256) void k_gemm(
    const ushort_t* __restrict__ Aph, const ushort_t* __restrict__ Apl,
    const float* __restrict__ Wt, const float* __restrict__ Wi,
    const float* __restrict__ biast, const float* __restrict__ biasi,
    const float* __restrict__ ws_ro, float* __restrict__ wsw,
    const float* __restrict__ txt, const float* __restrict__ img,
    ushort_t* __restrict__ Hph, ushort_t* __restrict__ Hpl, float* __restrict__ outf) {
  int mt = blockIdx.x / NPR, nt = blockIdx.x % NPR;
  int row0 = mt * 128;
  int col0 = nt * NTILE;
  int b = row0 / T_;
  int t0 = row0 % T_;
  bool is_txt = t0 < L_;
  const float* W = is_txt ? Wt : Wi;

  __shared__ __align__(16) ushort_t ash[128 * 40];
  __shared__ __align__(16) ushort_t asl[128 * 40];
  __shared__ __align__(16) ushort_t bsh[NTILE * 40];
  __shared__ __align__(16) ushort_t bsl[(NTERMS == 3) ? NTILE * 40 : 8];

  int tid = threadIdx.x;
  int w = tid >> 6, lane = tid & 63, quad = lane >> 4, lc = lane & 15;
  int rh = w >> 1, ch = w & 1;
  constexpr int NFR = NTILE / 32;

  f32x4 acc[4][NFR];
  #pragma unroll
  for (int m = 0; m < 4; ++m)
    #pragma unroll
    for (int n = 0; n < NFR; ++n) acc[m][n] = f32x4{0.f, 0.f, 0.f, 0.f};

  for (int kt = 0; kt < KDIM / 32; ++kt) {
    // ---- stage A: pure uint4 copies from pre-split planes ----
    {
      int r = tid >> 1, koff = (tid & 1) * 16;
      size_t abase = (size_t)(row0 + r) * KDIM + kt * 32 + koff;
      uint4 h0 = *(const uint4*)&Aph[abase];
      uint4 h1 = *(const uint4*)&Aph[abase + 8];
      uint4 l0 = *(const uint4*)&Apl[abase];
      uint4 l1 = *(const uint4*)&Apl[abase + 8];
      *(uint4*)&ash[r * 40 + koff]     = h0;
      *(uint4*)&ash[r * 40 + koff + 8] = h1;
      *(uint4*)&asl[r * 40 + koff]     = l0;
      *(uint4*)&asl[r * 40 + koff + 8] = l1;
    }
    // ---- stage W (f32 -> bf16 hi [+lo]): NTILE rows x 32 k ----
    {
      constexpr int NW = NTILE * 8 / 256;
      #pragma unroll
      for (int wc = 0; wc < NW; ++wc) {
        int idx = wc * 256 + tid;
        int rw = idx >> 3, c4 = idx & 7;
        float4 v = *(const float4*)(W + (size_t)(col0 + rw) * KDIM + kt * 32 + c4 * 4);
        ushort4 hh;
        hh.x = f2bf_rne(v.x); hh.y = f2bf_rne(v.y); hh.z = f2bf_rne(v.z); hh.w = f2bf_rne(v.w);
        *(ushort4*)&bsh[rw * 40 + c4 * 4] = hh;
        if (NTERMS == 3) {
          ushort4 ll;
          ll.x = f2bf_rne(v.x - __uint_as_float((unsigned)hh.x << 16));
          ll.y = f2bf_rne(v.y - __uint_as_float((unsigned)hh.y << 16));
          ll.z = f2bf_rne(v.z - __uint_as_float((unsigned)hh.z << 16));
          ll.w = f2bf_rne(v.w - __uint_as_float((unsigned)hh.w << 16));
          *(ushort4*)&bsl[rw * 40 + c4 * 4] = ll;
        }
      }
    }
    __syncthreads();

    bf16x8 afh[4], afl[4];
    #pragma unroll
    for (int m = 0; m < 4; ++m) {
      int ar = rh * 64 + m * 16 + lc;
      afh[m] = *(const bf16x8*)&ash[ar * 40 + quad * 8];
      afl[m] = *(const bf16x8*)&asl[ar * 40 + quad * 8];
    }
    #pragma unroll
    for (int n = 0; n < NFR; ++n) {
      int br = ch * (NTILE / 2) + n * 16 + lc;
      bf16x8 bh = *(const bf16x8*)&bsh[br * 40 + quad * 8];
      if (NTERMS == 3) {
        bf16x8 bl = *(const bf16x8*)&bsl[br * 40 + quad * 8];
        #pragma unroll
        for (int m = 0; m < 4; ++m) {
          acc[m][n] = __builtin_amdgcn_mfma_f32_16x16x32_bf16(afl[m], bh, acc[m][n], 0, 0, 0);
          acc[m][n] = __builtin_amdgcn_mfma_f32_16x16x32_bf16(afh[m], bl, acc[m][n], 0, 0, 0);
          acc[m][n] = __builtin_amdgcn_mfma_f32_16x16x32_bf16(afh[m], bh, acc[m][n], 0, 0, 0);
        }
      } else {
        #pragma unroll
        for (int m = 0; m < 4; ++m) {
          acc[m][n] = __builtin_amdgcn_mfma_f32_16x16x32_bf16(afl[m], bh, acc[m][n], 0, 0, 0);
          acc[m][n] = __builtin_amdgcn_mfma_f32_16x16x32_bf16(afh[m], bh, acc[m][n], 0, 0, 0);
        }
      }
    }
    __syncthreads();
  }

  const float* e = ws_ro + (is_txt ? O_ETXT : O_EIMG) + (size_t)b * SIXD;
  const float* bias = is_txt ? biast : biasi;
  #pragma unroll
  for (int m = 0; m < 4; ++m) {
    #pragma unroll
    for (int n = 0; n < NFR; ++n) {
      #pragma unroll
      for (int r = 0; r < 4; ++r) {
        int rg = row0 + rh * 64 + m * 16 + quad * 4 + r;
        int cg = col0 + ch * (NTILE / 2) + n * 16 + lc;
        float val = acc[m][n][r];
        int tt = rg % T_;
        if (EPI == 0) {
          int which = cg >> 9, h = (cg >> 7) & 3, dd = cg & 127;
          float* dst = wsw + (which == 0 ? O_Q : which == 1 ? O_K : O_V)
                     + (((size_t)b * NH_ + h) * T_ + tt) * HD_ + dd;
          *dst = val;
        } else if (EPI == 1) {
          float g = e[1024 + cg];
          float res = is_txt ? txt[((size_t)b * L_ + tt) * D_ + cg]
                             : img[((size_t)b * N_ + (tt - L_)) * D_ + cg];
          wsw[O_X2 + (size_t)rg * D_ + cg] = res + g * val;
        } else if (EPI == 2) {
          float x = val + bias[cg];
          float z = 0.7978845608028654f * (x + 0.044715f * x * x * x);
          z = fminf(fmaxf(z, -40.f), 40.f);
          float u = __expf(-2.f * z);
          float th = (1.f - u) / (1.f + u);
          float hv = 0.5f * x * (1.f + th);
          ushort_t hh = f2bf_rne(hv);
          Hph[(size_t)rg * FF_ + cg] = hh;
          Hpl[(size_t)rg * FF_ + cg] = f2bf_rne(hv - __uint_as_float((unsigned)hh << 16));
        } else {
          float g = e[2560 + cg];
          float v2 = ws_ro[O_X2 + (size_t)rg * D_ + cg] + g * (val + bias[cg]);
          size_t oi = is_txt ? ((size_t)b * L_ + tt) * D_ + cg
                             : (size_t)B_ * L_ * D_ + ((size_t)b * N_ + (tt - L_)) * D_ + cg;
          outf[oi] = v2;
        }
      }
    }
  }
}

// ---------------- prep: rope+mod on Q (in place f32), K -> pre-split bf16 hi/lo planes ----------------
__global__ __launch_bounds__(256) void k_prep(float* __restrict__ wsw, const float* __restrict__ rope) {
  int idx = blockIdx.x * 256 + threadIdx.x;  // B*NH*T*64 = 1,310,720
  int i = idx & 63;
  int p = idx >> 6;                 // bh*T + t
  int t = p % T_;
  int bh = p / T_;
  size_t base = (size_t)p * HD_ + 2 * i;
  float* Q = wsw + O_Q;
  float* K = wsw + O_K;
  float k0 = K[base], k1 = K[base + 1];
  if (t >= L_) {
    int n = t - L_;
    float c = rope[(size_t)n * HD_ + 2 * i];
    float s = rope[(size_t)n * HD_ + 2 * i + 1];
    float m = wsw[O_MOD + (size_t)bh * N_ + n];
    float q0 = Q[base], q1 = Q[base + 1];
    Q[base]     = (q0 * c - q1 * s) * m;
    Q[base + 1] = (q1 * c + q0 * s) * m;
    float nk0 = (k0 * c - k1 * s) * m;
    float nk1 = (k1 * c + k0 * s) * m;
    k0 = nk0; k1 = nk1;
  }
  ushort_t h0 = f2bf_rne(k0), h1 = f2bf_rne(k1);
  ushort_t l0 = f2bf_rne(k0 - __uint_as_float((unsigned)h0 << 16));
  ushort_t l1 = f2bf_rne(k1 - __uint_as_float((unsigned)h1 << 16));
  ushort_t* KH = (ushort_t*)(wsw + O_XIN2);
  ushort_t* KL = KH + QSZ;
  *(unsigned*)&KH[(size_t)p * HD_ + 2 * i] = (unsigned)h0 | ((unsigned)h1 << 16);
  *(unsigned*)&KL[(size_t)p * HD_ + 2 * i] = (unsigned)l0 | ((unsigned)l1 << 16);
}

// ---------------- V f32 [bh][t][128] -> Vt bf16 [bh][d][T] (tiled transpose) ----------------
__global__ __launch_bounds__(256) void k_vt(const float* __restrict__ ws_ro, float* __restrict__ wsw) {
  int bh = blockIdx.x & 7;
  int tt = blockIdx.x >> 3;      // 0..39
  int t0 = tt * 64;
  __shared__ ushort_t vls[128 * 72];
  int tid = threadIdx.x;
  {
    int tr = tid & 63, dc = tid >> 6;  // dc: 0..3 (32-d chunk)
    const float4* src = (const float4*)(ws_ro + O_V + ((size_t)bh * T_ + t0 + tr) * HD_ + dc * 32);
    #pragma unroll
    for (int f = 0; f < 8; ++f) {
      float4 v = src[f];
      int d = dc * 32 + f * 4;
      vls[(d + 0) * 72 + tr] = f2bf_rne(v.x);
      vls[(d + 1) * 72 + tr] = f2bf_rne(v.y);
      vls[(d + 2) * 72 + tr] = f2bf_rne(v.z);
      vls[(d + 3) * 72 + tr] = f2bf_rne(v.w);
    }
  }
  __syncthreads();
  {
    int d = tid >> 1, th = (tid & 1) * 32;
    unsigned* Vt32 = (unsigned*)(wsw + O_X2);
    size_t obase = (((size_t)bh * HD_ + d) * T_ + t0 + th) >> 1;
    #pragma unroll
    for (int k = 0; k < 16; ++k) {
      unsigned lo = vls[d * 72 + th + 2 * k];
      unsigned hi = vls[d * 72 + th + 2 * k + 1];
      Vt32[obase + k] = lo | (hi << 16);
    }
  }
}

// ---------------- MFMA flash attention v6: K in LDS (staged), V direct from L2 ----------------
// grid = 8 bh x 40 qg = 320 blocks, 256 thr (4 waves x 16 q-rows). LDS 44 KB -> 3 blocks/CU.
// V-frag loads have a long slack window (issued before softmax, consumed after).
__global__ __launch_bounds__(256) void k_attn6(const float* __restrict__ ws_ro, float* __restrict__ wsw) {
  int bh = blockIdx.x & 7;            // bh-per-XCD swizzle for L2 locality
  int qg = blockIdx.x >> 3;           // 0..39
  int b = bh >> 2, h = bh & 3;
  int tid = threadIdx.x;
  int w = tid >> 6, lane = tid & 63, quad = lane >> 4, lc = lane & 15;
  int q0 = (qg * 4 + w) * 16;
  float scale = (q0 < L_) ? SCALE_ : ws_ro[O_EFF + b];

  const ushort_t* Khs = (const ushort_t*)(ws_ro + O_XIN2);
  const ushort_t* Kls = Khs + QSZ;
  const ushort_t* Vts = (const ushort_t*)(ws_ro + O_X2) + (size_t)bh * HD_ * T_;

  __shared__ __align__(16) ushort_t ksh[64 * 136];
  __shared__ __align__(16) ushort_t ksl[64 * 136];
  __shared__ __align__(16) ushort_t ps[4 * 16 * 72];
  ushort_t* pw = &ps[w * 1152];

  // ---- Q frags direct from global f32 (scaled + hi/lo split, once) ----
  bf16x8 qh[4], ql[4];
  {
    const float* qrowp = ws_ro + O_Q + ((size_t)bh * T_ + q0 + lc) * HD_ + quad * 8;
    #pragma unroll
    for (int k2 = 0; k2 < 4; ++k2) {
      float4 a = *(const float4*)(qrowp + k2 * 32);
      float4 c = *(const float4*)(qrowp + k2 * 32 + 4);
      float v[8] = {a.x, a.y, a.z, a.w, c.x, c.y, c.z, c.w};
      #pragma unroll
      for (int e = 0; e < 8; ++e) {
        float x = v[e] * scale;
        ushort_t hh = f2bf_rne(x);
        float hf = __uint_as_float((unsigned)hh << 16);
        qh[k2][e] = (short)hh;
        ql[k2][e] = (short)f2bf_rne(x - hf);
      }
    }
  }

  f32x4 o[8];
  #pragma unroll
  for (int i = 0; i < 8; ++i) o[i] = f32x4{0.f, 0.f, 0.f, 0.f};
  float m_r[4] = {-1e30f, -1e30f, -1e30f, -1e30f};
  float l_r[4] = {0.f, 0.f, 0.f, 0.f};

  for (int kt = 0; kt < T_ / 64; ++kt) {
    // ---- stage K hi/lo (64 rows x 128) — pure copies ----
    {
      int row = tid >> 2, cs = tid & 3;
      size_t gbase = ((size_t)bh * T_ + kt * 64 + row) * HD_;
      #pragma unroll
      for (int cc = 0; cc < 4; ++cc) {
        int c = cs + cc * 4;                 // 0..15: 16 uint4 = 128 ushorts
        *(uint4*)&ksh[row * 136 + c * 8] = *(const uint4*)&Khs[gbase + c * 8];
        *(uint4*)&ksl[row * 136 + c * 8] = *(const uint4*)&Kls[gbase + c * 8];
      }
    }
    __syncthreads();

    // ---- S = Q K^T (3-term hi/lo), 4 x 16-key n-tiles ----
    f32x4 s[4];
    #pragma unroll
    for (int nt = 0; nt < 4; ++nt) s[nt] = f32x4{0.f, 0.f, 0.f, 0.f};
    #pragma unroll
    for (int k2 = 0; k2 < 4; ++k2) {
      int ko = k2 * 32 + quad * 8;
      #pragma unroll
      for (int nt = 0; nt < 4; ++nt) {
        bf16x8 kh = *(const bf16x8*)&ksh[(nt * 16 + lc) * 136 + ko];
        bf16x8 kl = *(const bf16x8*)&ksl[(nt * 16 + lc) * 136 + ko];
        s[nt] = __builtin_amdgcn_mfma_f32_16x16x32_bf16(ql[k2], kh, s[nt], 0, 0, 0);
        s[nt] = __builtin_amdgcn_mfma_f32_16x16x32_bf16(qh[k2], kl, s[nt], 0, 0, 0);
        s[nt] = __builtin_amdgcn_mfma_f32_16x16x32_bf16(qh[k2], kh, s[nt], 0, 0, 0);
      }
    }

    // ---- V frags batch 0 (keys 0-31): issued BEFORE softmax -> L2 latency hidden ----
    const ushort_t* Vb = Vts + kt * 64;
    bf16x8 vb0[8];
    #pragma unroll
    for (int dt = 0; dt < 8; ++dt)
      vb0[dt] = *(const bf16x8*)&Vb[(size_t)(dt * 16 + lc) * T_ + quad * 8];

    // ---- online softmax over 64 keys ----
    float alpha[4];
    #pragma unroll
    for (int r = 0; r < 4; ++r) {
      float rm = fmaxf(fmaxf(s[0][r], s[1][r]), fmaxf(s[2][r], s[3][r]));
      rm = fmaxf(rm, __shfl_xor(rm, 1, 64));
      rm = fmaxf(rm, __shfl_xor(rm, 2, 64));
      rm = fmaxf(rm, __shfl_xor(rm, 4, 64));
      rm = fmaxf(rm, __shfl_xor(rm, 8, 64));
      float mn = fmaxf(m_r[r], rm);
      alpha[r] = __expf(m_r[r] - mn);
      m_r[r] = mn;
      float p0 = __expf(s[0][r] - mn);
      float p1 = __expf(s[1][r] - mn);
      float p2 = __expf(s[2][r] - mn);
      float p3 = __expf(s[3][r] - mn);
      float rs = (p0 + p1) + (p2 + p3);
      rs += __shfl_xor(rs, 1, 64);
      rs += __shfl_xor(rs, 2, 64);
      rs += __shfl_xor(rs, 4, 64);
      rs += __shfl_xor(rs, 8, 64);
      l_r[r] = l_r[r] * alpha[r] + rs;
      int prow = quad * 4 + r;
      pw[prow * 72 + lc]      = f2bf_rne(p0);
      pw[prow * 72 + lc + 16] = f2bf_rne(p1);
      pw[prow * 72 + lc + 32] = f2bf_rne(p2);
      pw[prow * 72 + lc + 48] = f2bf_rne(p3);
    }
    #pragma unroll
    for (int dt = 0; dt < 8; ++dt) {
      #pragma unroll
      for (int r = 0; r < 4; ++r) o[dt][r] *= alpha[r];
    }

    // ---- V frags batch 1 (keys 32-63) ----
    bf16x8 vb1[8];
    #pragma unroll
    for (int dt = 0; dt < 8; ++dt)
      vb1[dt] = *(const bf16x8*)&Vb[(size_t)(dt * 16 + lc) * T_ + 32 + quad * 8];

    // ---- P relayout (wave-private LDS, no barrier) + O += P V ----
    bf16x8 pa0 = *(const bf16x8*)&pw[lc * 72 + quad * 8];
    bf16x8 pa1 = *(const bf16x8*)&pw[lc * 72 + 32 + quad * 8];
    #pragma unroll
    for (int dt = 0; dt < 8; ++dt)
      o[dt] = __builtin_amdgcn_mfma_f32_16x16x32_bf16(pa0, vb0[dt], o[dt], 0, 0, 0);
    #pragma unroll
    for (int dt = 0; dt < 8; ++dt)
      o[dt] = __builtin_amdgcn_mfma_f32_16x16x32_bf16(pa1, vb1[dt], o[dt], 0, 0, 0);
    __syncthreads();
  }

  // ---- normalize + write bf16 hi/lo planes into ATTN [b][t][h*128+d] ----
  ushort_t* ATh = (ushort_t*)(wsw + O_ATTN);
  ushort_t* ATl = ATh + QSZ;
  int trow0 = q0 + quad * 4;
  #pragma unroll
  for (int r = 0; r < 4; ++r) {
    float inv = 1.0f / l_r[r];
    size_t base = ((size_t)b * T_ + (trow0 + r)) * D_ + h * HD_ + lc;
    #pragma unroll
    for (int dt = 0; dt < 8; ++dt) {
      float v = o[dt][r] * inv;
      ushort_t hh = f2bf_rne(v);
      ATh[base + dt * 16] = hh;
      ATl[base + dt * 16] = f2bf_rne(v - __uint_as_float((unsigned)hh << 16));
    }
  }
}

extern "C" void kernel_launch(void* const* d_in, const int* in_sizes, int n_in,
                              void* d_out, int out_size, void* d_ws, size_t ws_size,
                              hipStream_t stream) {
  (void)in_sizes; (void)n_in; (void)out_size; (void)ws_size;
  const float* txt    = (const float*)d_in[0];
  const float* img    = (const float*)d_in[1];
  const float* vec    = (const float*)d_in[2];
  const float* rope   = (const float*)d_in[3];
  const float* stemp  = (const float*)d_in[4];
  const float* sspat  = (const float*)d_in[5];
  const float* i_aw   = (const float*)d_in[6];
  const float* i_ab   = (const float*)d_in[7];
  const float* i_anw  = (const float*)d_in[8];
  const float* t_aw   = (const float*)d_in[9];
  const float* t_ab   = (const float*)d_in[10];
  const float* t_anw  = (const float*)d_in[11];
  const float* t_qkvw = (const float*)d_in[12];
  const float* i_qkvw = (const float*)d_in[13];
  const float* t_outw = (const float*)d_in[14];
  const float* i_outw = (const float*)d_in[15];
  const float* modw   = (const float*)d_in[16];
  const float* modb   = (const float*)d_in[17];
  const float* i_n2w  = (const float*)d_in[18];
  const float* t_n2w  = (const float*)d_in[19];
  const float* i_f1w  = (const float*)d_in[20];
  const float* i_f1b  = (const float*)d_in[21];
  const float* i_f2w  = (const float*)d_in[22];
  const float* i_f2b  = (const float*)d_in[23];
  const float* t_f1w  = (const float*)d_in[24];
  const float* t_f1b  = (const float*)d_in[25];
  const float* t_f2w  = (const float*)d_in[26];
  const float* t_f2b  = (const float*)d_in[27];
  float* ws = (float*)d_ws;
  float* out = (float*)d_out;
  ushort_t* XNh  = (ushort_t*)(ws + O_XN);   ushort_t* XNl  = XNh + QSZ;
  ushort_t* ATh  = (ushort_t*)(ws + O_ATTN); ushort_t* ATl  = ATh + QSZ;
  ushort_t* XI2h = (ushort_t*)(ws + O_XIN2); ushort_t* XI2l = XI2h + QSZ;
  ushort_t* Hh   = (ushort_t*)(ws + O_H);    ushort_t* Hl   = Hh + 4 * QSZ;

  hipLaunchKernelGGL(k_adaln, dim3(48), dim3(256), 0, stream, vec, t_aw, t_ab, i_aw, i_ab, ws);
  hipLaunchKernelGGL(k_mod, dim3(64), dim3(256), 0, stream, sspat, modw, modb, stemp, ws);
  hipLaunchKernelGGL((k_rmsmod<true>), dim3(MROWS), dim3(256), 0, stream,
                     txt, img, (const float*)nullptr, t_anw, i_anw, 0, 512, ws, XNh, XNl);
  // QKV: N=1536, 3-term, K=512
  hipLaunchKernelGGL((k_gemm<128, 3, 512, 12, 0>), dim3(40 * 12), dim3(256), 0, stream,
                     XNh, XNl, t_qkvw, i_qkvw, nullptr, nullptr, ws, ws, txt, img,
                     (ushort_t*)nullptr, (ushort_t*)nullptr, nullptr);
  hipLaunchKernelGGL(k_prep, dim3(5120), dim3(256), 0, stream, ws, rope);
  hipLaunchKernelGGL(k_vt, dim3(320), dim3(256), 0, stream, ws, ws);
  hipLaunchKernelGGL(k_attn6, dim3(320), dim3(256), 0, stream, ws, ws);
  // proj: N=512, 2-term, K=512
  hipLaunchKernelGGL((k_gemm<64, 2, 512, 8, 1>), dim3(40 * 8), dim3(256), 0, stream,
                     ATh, ATl, t_outw, i_outw, nullptr, nullptr, ws, ws, txt, img,
                     (ushort_t*)nullptr, (ushort_t*)nullptr, nullptr);
  hipLaunchKernelGGL((k_rmsmod<false>), dim3(MROWS), dim3(256), 0, stream,
                     (const float*)nullptr, (const float*)nullptr, ws + O_X2, t_n2w, i_n2w,
                     1536, 2048, ws, XI2h, XI2l);
  // fc1: N=2048, 2-term, K=512
  hipLaunchKernelGGL((k_gemm<128, 2, 512, 16, 2>), dim3(40 * 16), dim3(256), 0, stream,
                     XI2h, XI2l, t_f1w, i_f1w, t_f1b, i_f1b, ws, ws, txt, img, Hh, Hl, nullptr);
  // fc2: N=512, 2-term, K=2048
  hipLaunchKernelGGL((k_gemm<64, 2, 2048, 8, 3>), dim3(40 * 8), dim3(256), 0, stream,
                     Hh, Hl, t_f2w, i_f2w, t_f2b, i_f2b, ws, ws, txt, img,
                     (ushort_t*)nullptr, (ushort_t*)nullptr, out);
}